// Round 2
// baseline (342.455 us; speedup 1.0000x reference)
//
#include <hip/hip_runtime.h>

// Problem constants (from reference: B=256, S=64, R=128, F=1536, D=256)
constexpr int Bc = 256;
constexpr int Sc = 64;
constexpr int Rc = 128;
constexpr int Fc = 1536;
constexpr int Dc = 256;  // F/6

// ---------------------------------------------------------------------------
// Kernel 1: per-row (b,r) statistics over the F=1536 axis.
//   s0[row] = sum_d  r_re*(h_re*t_re + h_im*t_im) + r_im*(h_re*t_im - h_im*t_re)
//   q[row]  = sum_f  tri[row,f]^2          (= sum of all six slices' sumsq)
// One wave (64 lanes) per row; each lane loads one float4 per slice.
// 4 waves per 256-thread block -> 4 rows per block.
// ---------------------------------------------------------------------------
__device__ __forceinline__ void accum_term(float h_re, float h_im,
                                           float r_re, float r_im,
                                           float t_re, float t_im,
                                           float& s0, float& q) {
  s0 += r_re * (h_re * t_re + h_im * t_im) + r_im * (h_re * t_im - h_im * t_re);
  q  += h_re * h_re + h_im * h_im + r_re * r_re + r_im * r_im + t_re * t_re + t_im * t_im;
}

__global__ __launch_bounds__(256) void rowstats_kernel(
    const float* __restrict__ tri, float* __restrict__ s0_out,
    float* __restrict__ q_out) {
  const int wid  = threadIdx.x >> 6;   // wave id in block (0..3)
  const int lane = threadIdx.x & 63;   // lane in wave
  const int row  = blockIdx.x * 4 + wid;  // (b*R + r), < B*R

  const float4* p4 = reinterpret_cast<const float4*>(tri + (size_t)row * Fc);
  // slice i starts at float offset i*D = i*256 -> float4 offset i*64
  const float4 hre = p4[lane +   0];
  const float4 him = p4[lane +  64];
  const float4 rre = p4[lane + 128];
  const float4 rim = p4[lane + 192];
  const float4 tre = p4[lane + 256];
  const float4 tim = p4[lane + 320];

  float s0 = 0.f, q = 0.f;
  accum_term(hre.x, him.x, rre.x, rim.x, tre.x, tim.x, s0, q);
  accum_term(hre.y, him.y, rre.y, rim.y, tre.y, tim.y, s0, q);
  accum_term(hre.z, him.z, rre.z, rim.z, tre.z, tim.z, s0, q);
  accum_term(hre.w, him.w, rre.w, rim.w, tre.w, tim.w, s0, q);

  // wave (64-lane) butterfly reduce
  #pragma unroll
  for (int off = 32; off > 0; off >>= 1) {
    s0 += __shfl_down(s0, off, 64);
    q  += __shfl_down(q, off, 64);
  }
  if (lane == 0) {
    s0_out[row] = s0;
    q_out[row]  = q;
  }
}

// ---------------------------------------------------------------------------
// Kernel 2: score + regul accumulation over (b,s,r).
//   a      = (alpha - 0.1) * mask[b,s]
//   sp_sum += softplus(-a^3 * s0[b,r])
//   aq_sum += a^2 * q[b,r]
// Each thread handles 4 consecutive r. Double atomics, one pair per block.
// ---------------------------------------------------------------------------
__global__ __launch_bounds__(256) void score_kernel(
    const float* __restrict__ alpha, const float* __restrict__ mask,
    const float* __restrict__ s0_arr, const float* __restrict__ q_arr,
    double* __restrict__ acc) {
  const int t   = blockIdx.x * 256 + threadIdx.x;
  const int idx = t * 4;              // flat index into (B,S,R), < B*S*R
  const int r   = idx & (Rc - 1);     // idx % 128
  const int bs  = idx >> 7;           // idx / 128
  const int b   = bs >> 6;            // bs / 64

  const float m = mask[bs];
  const float4 al  = *reinterpret_cast<const float4*>(alpha + idx);
  const float4 s0v = *reinterpret_cast<const float4*>(s0_arr + b * Rc + r);
  const float4 qv  = *reinterpret_cast<const float4*>(q_arr + b * Rc + r);

  float sp_sum = 0.f, aq_sum = 0.f;
  {
    float a = (al.x - 0.1f) * m;
    float sc = -(a * a * a) * s0v.x;
    sp_sum += fmaxf(sc, 0.f) + log1pf(__expf(-fabsf(sc)));
    aq_sum += a * a * qv.x;
  }
  {
    float a = (al.y - 0.1f) * m;
    float sc = -(a * a * a) * s0v.y;
    sp_sum += fmaxf(sc, 0.f) + log1pf(__expf(-fabsf(sc)));
    aq_sum += a * a * qv.y;
  }
  {
    float a = (al.z - 0.1f) * m;
    float sc = -(a * a * a) * s0v.z;
    sp_sum += fmaxf(sc, 0.f) + log1pf(__expf(-fabsf(sc)));
    aq_sum += a * a * qv.z;
  }
  {
    float a = (al.w - 0.1f) * m;
    float sc = -(a * a * a) * s0v.w;
    sp_sum += fmaxf(sc, 0.f) + log1pf(__expf(-fabsf(sc)));
    aq_sum += a * a * qv.w;
  }

  // block reduce (4 waves)
  #pragma unroll
  for (int off = 32; off > 0; off >>= 1) {
    sp_sum += __shfl_down(sp_sum, off, 64);
    aq_sum += __shfl_down(aq_sum, off, 64);
  }
  __shared__ float lds[8];
  const int lane = threadIdx.x & 63, wid = threadIdx.x >> 6;
  if (lane == 0) {
    lds[wid]     = sp_sum;
    lds[wid + 4] = aq_sum;
  }
  __syncthreads();
  if (threadIdx.x == 0) {
    float spb = lds[0] + lds[1] + lds[2] + lds[3];
    float aqb = lds[4] + lds[5] + lds[6] + lds[7];
    atomicAdd(acc + 0, (double)spb);
    atomicAdd(acc + 1, (double)aqb);
  }
}

// ---------------------------------------------------------------------------
// Kernel 3: finalize. Sum mask (numtrue), combine accumulators into out[0].
// ---------------------------------------------------------------------------
__global__ __launch_bounds__(256) void finalize_kernel(
    const float* __restrict__ mask, const double* __restrict__ acc,
    float* __restrict__ out) {
  float s = 0.f;
  for (int i = threadIdx.x; i < Bc * Sc; i += 256) s += mask[i];
  #pragma unroll
  for (int off = 32; off > 0; off >>= 1) s += __shfl_down(s, off, 64);
  __shared__ float lds[4];
  const int lane = threadIdx.x & 63, wid = threadIdx.x >> 6;
  if (lane == 0) lds[wid] = s;
  __syncthreads();
  if (threadIdx.x == 0) {
    double numtrue = (double)(lds[0] + lds[1] + lds[2] + lds[3]);
    double denom   = (double)Bc * (double)Sc * (double)Rc * (double)Dc;  // B*S*R*D
    out[0] = (float)(acc[0] / numtrue + 0.01 * acc[1] / denom);
  }
}

// ---------------------------------------------------------------------------
extern "C" void kernel_launch(void* const* d_in, const int* in_sizes, int n_in,
                              void* d_out, int out_size, void* d_ws, size_t ws_size,
                              hipStream_t stream) {
  const float* tri   = (const float*)d_in[0];  // (B, R, F)
  const float* alpha = (const float*)d_in[1];  // (B, S, R)
  const float* mask  = (const float*)d_in[2];  // (B, S)
  float* out = (float*)d_out;

  // workspace layout: [0,64): 2 double accumulators (+pad); then s0, q arrays
  double* acc    = (double*)d_ws;
  float*  s0_arr = (float*)((char*)d_ws + 64);
  float*  q_arr  = s0_arr + Bc * Rc;

  hipMemsetAsync(d_ws, 0, 64, stream);

  rowstats_kernel<<<(Bc * Rc) / 4, 256, 0, stream>>>(tri, s0_arr, q_arr);
  score_kernel<<<(Bc * Sc * Rc) / (4 * 256), 256, 0, stream>>>(alpha, mask, s0_arr,
                                                               q_arr, acc);
  finalize_kernel<<<1, 256, 0, stream>>>(mask, acc, out);
}